// Round 22
// baseline (252.955 us; speedup 1.0000x reference)
//
#include <hip/hip_runtime.h>
#include <cstdint>

#define Bq 2
#define Tq 2048
#define Dq 1024
#define Hq 16
#define FFNq 4096
#define NCHUNK 32
#define ROWS (Bq*Tq)   // 4096
#define STW 5120       // 64x80 (or 80x64) state/tile words

typedef unsigned short u16;
typedef __attribute__((ext_vector_type(4))) float f32x4;

enum { ACT_NONE = 0, ACT_ELU1 = 1, ACT_GELU = 2 };

// gfx950 unified VGPR/AGPR file: "+v" is correct (r11: "+a" regressed).
// r14: do NOT fully unroll the pipeline loop. r18: NPH=4 regressed; NPH=2 optimum.
// r20/r21: waves/CU + blocks/CU (TLP) are the active levers at this schedule.
#define MFMA16(acc, a, b) \
  asm("v_mfma_f32_16x16x32_bf16 %0, %1, %2, %0" : "+v"(acc) : "v"(a), "v"(b))
#define VMWAIT(N) asm volatile("s_waitcnt vmcnt(" #N ")" ::: "memory")

__device__ __forceinline__ u16 f2bf(float f) {
  uint32_t u = __float_as_uint(f);
  uint32_t r = (u + 0x7FFFu + ((u >> 16) & 1u)) >> 16;
  return (u16)r;
}
__device__ __forceinline__ float bf2f(u16 u) {
  return __uint_as_float(((uint32_t)u) << 16);
}
__device__ __forceinline__ float bflo(uint32_t w) { return __uint_as_float(w << 16); }
__device__ __forceinline__ float bfhi(uint32_t w) { return __uint_as_float(w & 0xffff0000u); }

__device__ __forceinline__ void gload16(const void* g, void* l) {
  __builtin_amdgcn_global_load_lds(
      (const __attribute__((address_space(1))) uint32_t*)g,
      (__attribute__((address_space(3))) uint32_t*)l, 16, 0, 0);
}

// bijective XCD swizzle (nwg % 8 == 0 for all our grids)
__device__ __forceinline__ void xcd_swizzle(int& bx, int& by) {
  const int gx = gridDim.x;
  const int nwg = gx * gridDim.y;
  int flat = by * gx + bx;
  flat = (flat & 7) * (nwg >> 3) + (flat >> 3);
  bx = flat % gx;
  by = flat / gx;
}

// ---------------- merged weight convert+transpose: 6 matrices, one launch ----------------
__global__ __launch_bounds__(256) void wconv_all(
    const float* __restrict__ q_w, const float* __restrict__ k_w,
    const float* __restrict__ v_w, const float* __restrict__ o_w,
    const float* __restrict__ f1_w, const float* __restrict__ f2_w,
    u16* __restrict__ qkvT, u16* __restrict__ owT,
    u16* __restrict__ f1T, u16* __restrict__ f2T)
{
  const int bid = blockIdx.x;
  const float* src; u16* dst; int Kd, N, bx, by;
  if (bid < 1024) {          // q,k,v,o: 4 x 256 tiles (1024x1024)
    const int m = bid >> 8, t = bid & 255;
    src = (m == 0) ? q_w : (m == 1) ? k_w : (m == 2) ? v_w : o_w;
    dst = (m == 3) ? owT : qkvT + (size_t)m * 1024 * 1024;
    Kd = 1024; N = 1024; bx = t & 15; by = t >> 4;
  } else if (bid < 2048) {   // f1: 1024x4096
    const int t = bid - 1024;
    src = f1_w; dst = f1T; Kd = 1024; N = 4096; bx = t & 63; by = t >> 6;
  } else {                   // f2: 4096x1024
    const int t = bid - 2048;
    src = f2_w; dst = f2T; Kd = 4096; N = 1024; bx = t & 15; by = t >> 4;
  }
  __shared__ float tb[64][65];
  const int n0 = bx * 64, k0 = by * 64;
  const int tid = threadIdx.x;
  #pragma unroll
  for (int r = 0; r < 4; ++r) {
    const int s = tid + r * 256;           // 0..1023
    const int kk = s >> 4, nn = (s & 15) << 2;
    const float4 v = *(const float4*)(src + (size_t)(k0 + kk) * N + n0 + nn);
    tb[kk][nn] = v.x; tb[kk][nn+1] = v.y; tb[kk][nn+2] = v.z; tb[kk][nn+3] = v.w;
  }
  __syncthreads();
  const int n = tid >> 2;
  const int ks = (tid & 3) << 4;
  uint32_t pk[8];
  #pragma unroll
  for (int j = 0; j < 8; ++j) {
    const float a = tb[ks + 2*j][n];
    const float c = tb[ks + 2*j + 1][n];
    pk[j] = (uint32_t)f2bf(a) | ((uint32_t)f2bf(c) << 16);
  }
  u16* drow = dst + (size_t)(n0 + n) * Kd + k0 + ks;
  *(uint4*)(drow)     = make_uint4(pk[0], pk[1], pk[2], pk[3]);
  *(uint4*)(drow + 8) = make_uint4(pk[4], pk[5], pk[6], pk[7]);
}

// ---------------- LayerNorm: fp32 in, bf16 out ----------------
__global__ __launch_bounds__(256) void ln_kernel(
    const float* __restrict__ x, const float* __restrict__ w,
    const float* __restrict__ b, u16* __restrict__ outb)
{
  const int row = blockIdx.x;
  const int tid = threadIdx.x;
  const float* xr = x + (size_t)row * Dq;
  float4 v = *(const float4*)(xr + tid * 4);
  float s  = v.x + v.y + v.z + v.w;
  float s2 = v.x*v.x + v.y*v.y + v.z*v.z + v.w*v.w;
  #pragma unroll
  for (int off = 32; off > 0; off >>= 1) {
    s  += __shfl_down(s,  off);
    s2 += __shfl_down(s2, off);
  }
  __shared__ float rs[4], rs2[4];
  const int wid = tid >> 6, lane = tid & 63;
  if (lane == 0) { rs[wid] = s; rs2[wid] = s2; }
  __syncthreads();
  const float ts  = rs[0] + rs[1] + rs[2] + rs[3];
  const float ts2 = rs2[0] + rs2[1] + rs2[2] + rs2[3];
  const float mean = ts * (1.f / Dq);
  const float var  = ts2 * (1.f / Dq) - mean * mean;
  const float rstd = rsqrtf(var + 1e-5f);
  const float4 wv = *(const float4*)(w + tid * 4);
  const float4 bv = *(const float4*)(b + tid * 4);
  float4 o;
  o.x = (v.x - mean) * rstd * wv.x + bv.x;
  o.y = (v.y - mean) * rstd * wv.y + bv.y;
  o.z = (v.z - mean) * rstd * wv.z + bv.z;
  o.w = (v.w - mean) * rstd * wv.w + bv.w;
  uint2 p;
  p.x = (uint32_t)f2bf(o.x) | ((uint32_t)f2bf(o.y) << 16);
  p.y = (uint32_t)f2bf(o.z) | ((uint32_t)f2bf(o.w) << 16);
  *(uint2*)(outb + (size_t)row * Dq + tid * 4) = p;
}

// ============ bf16 MFMA GEMM: geometry+depth+splitK templated, NB buffers ============
// NPH=2 sub-phases per K-step (r16/r17-validated T3->T5 mechanism; r18: NPH=4
// regressed): {read A+B1, stageA, bar, setprio MFMA half} {read B2, stageB,
// bar, setprio MFMA half} — same buffer/vmcnt invariants as the base loop.
template<int BM, int BN, int TW, int WM, int WN, int NB, int SK, int ACT,
         bool RES, bool F32OUT, bool QKVMODE, int NPH = 1>
__global__ __launch_bounds__(TW) void mgemm(
    const u16* __restrict__ A, const u16* __restrict__ BT,
    const float* __restrict__ b0, const float* __restrict__ b1,
    const float* __restrict__ b2, const float* __restrict__ res,
    void* __restrict__ C0, void* __restrict__ C1, void* __restrict__ C2,
    int M, int N, int Kd)
{
  constexpr int GA = (BM * 32) / (TW * 8);   // A gloads/thread/stage
  constexpr int GB = (BN * 32) / (TW * 8);
  constexpr int L  = GA + GB;
  constexpr int MR = BM / WM / 16;
  constexpr int NR = BN / WN / 16;
  constexpr int VMAIN = (NB - 2) * L;        // steady-state wait
  __shared__ u16 As[NB][BM * 32];
  __shared__ u16 Bs[NB][BN * 32];
  const int tid = threadIdx.x;
  const int lane = tid & 63, wid = tid >> 6;
  const int wr = wid / WN, wc = wid % WN;
  int bx = blockIdx.x, by = blockIdx.y;
  xcd_swizzle(bx, by);
  const int rowBase = by * BM;
  const int colBase = bx * BN;
  const int bz  = (SK > 1) ? (int)blockIdx.z : 0;
  const int kb0 = bz * (Kd / SK);

  f32x4 acc[MR][NR] = {};

  const int srow = tid >> 2;                                  // 0..TW/4-1
  const int skb  = (((tid & 3) ^ ((tid >> 3) & 3)) << 3);     // pre-swizzled source
  const u16* ag[GA];
  const u16* bg[GB];
  #pragma unroll
  for (int g = 0; g < GA; ++g)
    ag[g] = A  + (size_t)(rowBase + g * (TW / 4) + srow) * Kd + kb0 + skb;
  #pragma unroll
  for (int g = 0; g < GB; ++g)
    bg[g] = BT + (size_t)(colBase + g * (TW / 4) + srow) * Kd + kb0 + skb;

  const int fr = lane & 15, fq = lane >> 4;
  const int rsw = (fq ^ ((fr >> 1) & 3)) * 8;                 // swizzled read

  auto STAGE_A = [&](int buf, int k0) {
    #pragma unroll
    for (int g = 0; g < GA; ++g) gload16(ag[g] + k0, &As[buf][(g * TW + tid) * 8]);
  };
  auto STAGE_B = [&](int buf, int k0) {
    #pragma unroll
    for (int g = 0; g < GB; ++g) gload16(bg[g] + k0, &Bs[buf][(g * TW + tid) * 8]);
  };

  const int NT = (Kd / SK) >> 5;
  #pragma unroll
  for (int s = 0; s < NB - 1; ++s) { STAGE_A(s, s << 5); STAGE_B(s, s << 5); }
  int cur = 0, wbuf = NB - 1;
  for (int t = 0; t < NT; ++t) {
    const int rem = NT - t;
    if (rem >= NB - 1) {
      if constexpr (VMAIN == 2)      VMWAIT(2);
      else if constexpr (VMAIN == 3) VMWAIT(3);
      else if constexpr (VMAIN == 4) VMWAIT(4);
      else if constexpr (VMAIN == 6) VMWAIT(6);
      else                           VMWAIT(8);
    } else if (NB >= 4 && rem == 2) {
      if constexpr (L == 2)      VMWAIT(2);
      else if constexpr (L == 3) VMWAIT(3);
      else                       VMWAIT(4);
    } else {
      VMWAIT(0);
    }
    __builtin_amdgcn_s_barrier();
    asm volatile("" ::: "memory");
    const bool pf = (t + NB - 1 < NT);
    const int  pk = (t + NB - 1) << 5;
    if constexpr (NPH == 2) {
      f32x4 af[MR], bf_[NR];
      #pragma unroll
      for (int m = 0; m < MR; ++m)
        af[m] = *(const f32x4*)(&As[cur][(wr * (BM / WM) + m * 16 + fr) * 32 + rsw]);
      #pragma unroll
      for (int n = 0; n < NR / 2; ++n)
        bf_[n] = *(const f32x4*)(&Bs[cur][(wc * (BN / WN) + n * 16 + fr) * 32 + rsw]);
      if (pf) STAGE_A(wbuf, pk);
      __builtin_amdgcn_s_barrier();
      asm volatile("" ::: "memory");
      __builtin_amdgcn_s_setprio(1);
      #pragma unroll
      for (int m = 0; m < MR; ++m)
        #pragma unroll
        for (int n = 0; n < NR / 2; ++n)
          MFMA16(acc[m][n], af[m], bf_[n]);
      __builtin_amdgcn_s_setprio(0);
      #pragma unroll
      for (int n = NR / 2; n < NR; ++n)
        bf_[n] = *(const f32x4*)(&Bs[cur][(wc * (BN / WN) + n * 16 + fr) * 32 + rsw]);
      if (pf) STAGE_B(wbuf, pk);
      __builtin_amdgcn_s_barrier();
      asm volatile("" ::: "memory");
      __builtin_amdgcn_s_setprio(1);
      #pragma unroll
      for (int m = 0; m < MR; ++m)
        #pragma unroll
        for (int n = NR / 2; n < NR; ++n)
          MFMA16(acc[m][n], af[m], bf_[n]);
      __builtin_amdgcn_s_setprio(0);
      asm volatile("" ::: "memory");
    } else {
      if (pf) { STAGE_A(wbuf, pk); STAGE_B(wbuf, pk); }
      f32x4 af[MR], bf_[NR];
      #pragma unroll
      for (int m = 0; m < MR; ++m)
        af[m] = *(const f32x4*)(&As[cur][(wr * (BM / WM) + m * 16 + fr) * 32 + rsw]);
      #pragma unroll
      for (int n = 0; n < NR; ++n)
        bf_[n] = *(const f32x4*)(&Bs[cur][(wc * (BN / WN) + n * 16 + fr) * 32 + rsw]);
      #pragma unroll
      for (int m = 0; m < MR; ++m)
        #pragma unroll
        for (int n = 0; n < NR; ++n)
          MFMA16(acc[m][n], af[m], bf_[n]);
      asm volatile("" ::: "memory");
    }
    cur  = (cur  == NB - 1) ? 0 : cur + 1;
    wbuf = (wbuf == NB - 1) ? 0 : wbuf + 1;
  }

  if constexpr (SK > 1) {
    u16* pp = (u16*)C1 + (size_t)bz * ((size_t)M * N);   // contiguous dead region
    #pragma unroll
    for (int m = 0; m < MR; ++m) {
      #pragma unroll
      for (int n = 0; n < NR; ++n) {
        const int col = colBase + wc * (BN / WN) + n * 16 + fr;
        #pragma unroll
        for (int r = 0; r < 4; ++r) {
          const int row = rowBase + wr * (BM / WM) + m * 16 + fq * 4 + r;
          pp[(size_t)row * N + col] = f2bf(acc[m][n][r]);
        }
      }
    }
  } else if constexpr (QKVMODE) {
    const int wtype = colBase >> 10;               // 0=q 1=k 2=v (block-uniform)
    const float* bp = (wtype == 0) ? b0 : (wtype == 1) ? b1 : b2;
    u16* outp = (u16*)((wtype == 0) ? C0 : (wtype == 1) ? C1 : C2);
    const int colB = colBase & 1023;
    #pragma unroll
    for (int m = 0; m < MR; ++m) {
      #pragma unroll
      for (int n = 0; n < NR; ++n) {
        const int col = colB + wc * (BN / WN) + n * 16 + fr;
        const float bv = bp[col];
        #pragma unroll
        for (int r = 0; r < 4; ++r) {
          const int row = rowBase + wr * (BM / WM) + m * 16 + fq * 4 + r;
          float val = acc[m][n][r] + bv;
          if (wtype < 2) val = (val >= 0.f) ? (val + 1.f) : expf(val);
          outp[(size_t)row * Dq + col] = f2bf(val);
        }
      }
    }
  } else {
    #pragma unroll
    for (int m = 0; m < MR; ++m) {
      #pragma unroll
      for (int n = 0; n < NR; ++n) {
        const int col = colBase + wc * (BN / WN) + n * 16 + fr;
        const float bv = b0[col];
        #pragma unroll
        for (int r = 0; r < 4; ++r) {
          const int row = rowBase + wr * (BM / WM) + m * 16 + fq * 4 + r;
          float val = acc[m][n][r] + bv;
          if (ACT == ACT_ELU1)      val = (val >= 0.f) ? (val + 1.f) : expf(val);
          else if (ACT == ACT_GELU) val = 0.5f * val * (1.f + erff(val * 0.70710678118f));
          if (RES) val += res[(size_t)row * N + col];
          if (F32OUT) ((float*)C0)[(size_t)row * N + col] = val;
          else        ((u16*)C0)[(size_t)row * N + col] = f2bf(val);
        }
      }
    }
  }
}

// ---------------- FFN2 split-K reduce: out = p0 + p1 + bias + res ----------------
__global__ __launch_bounds__(256) void ffn2_reduce(
    const u16* __restrict__ p, const float* __restrict__ bias,
    const float* __restrict__ res, float* __restrict__ out)
{
  const size_t base = ((size_t)blockIdx.x * 256 + threadIdx.x) * 8;
  const size_t MN = (size_t)ROWS * Dq;
  const uint4 a0 = *(const uint4*)(p + base);
  const uint4 a1 = *(const uint4*)(p + MN + base);
  const int col = (int)(base & (Dq - 1));
  float r[8];
  const uint32_t w0[4] = {a0.x, a0.y, a0.z, a0.w};
  const uint32_t w1[4] = {a1.x, a1.y, a1.z, a1.w};
  #pragma unroll
  for (int j = 0; j < 4; ++j) {
    r[2*j]   = bflo(w0[j]) + bflo(w1[j]);
    r[2*j+1] = bfhi(w0[j]) + bfhi(w1[j]);
  }
  const float4 x0 = *(const float4*)(res + base);
  const float4 x1 = *(const float4*)(res + base + 4);
  float4 o0, o1;
  o0.x = r[0] + bias[col+0] + x0.x;  o0.y = r[1] + bias[col+1] + x0.y;
  o0.z = r[2] + bias[col+2] + x0.z;  o0.w = r[3] + bias[col+3] + x0.w;
  o1.x = r[4] + bias[col+4] + x1.x;  o1.y = r[5] + bias[col+5] + x1.y;
  o1.z = r[6] + bias[col+6] + x1.z;  o1.w = r[7] + bias[col+7] + x1.w;
  *(float4*)(out + base)     = o0;
  *(float4*)(out + base + 4) = o1;
}

// ---------------- decay head (reads bf16 xn) ----------------
__global__ __launch_bounds__(256) void declam_kernel(
    const u16* __restrict__ xn, const float* __restrict__ dec_w,
    const float* __restrict__ dec_b, float* __restrict__ llam)
{
  const int row = blockIdx.x;
  const int tid = threadIdx.x;
  const int h = tid & 15, part = tid >> 4;
  const u16* xr = xn + (size_t)row * Dq;
  float s = 0.f;
  #pragma unroll 4
  for (int i = 0; i < 64; ++i) {
    const int d = part * 64 + i;
    s += bf2f(xr[d]) * dec_w[d * Hq + h];
  }
  __shared__ float ps[256];
  ps[tid] = s;
  __syncthreads();
  if (tid < 16) {
    float t = dec_b[tid];
    #pragma unroll
    for (int p = 0; p < 16; ++p) t += ps[p * 16 + tid];
    float lam = 1.f / (1.f + expf(-t));
    lam = fmaxf(lam, 1e-8f);
    llam[(size_t)row * Hq + tid] = logf(lam);
  }
}

// ================= LION phase A (MFMA): intra + transposed state deltas =================
__global__ __launch_bounds__(256) void lion_chunk_kernel(
    const u16* __restrict__ qb, const u16* __restrict__ kb,
    const u16* __restrict__ vb, const float* __restrict__ llam,
    u16* __restrict__ intra, u16* __restrict__ dS,
    u16* __restrict__ dR, float* __restrict__ lwout)
{
  const int c  = blockIdx.x;
  const int bh = blockIdx.y;
  const int b = bh >> 4, h = bh & 15;
  const int tid = threadIdx.x;
  const int lane = tid & 63, w = tid >> 6;
  const int fr = lane & 15, fq = lane >> 4;

  __shared__ __align__(16) u16 lds[37120];
  u16* qs   = lds;              // [64][80]
  u16* ks   = lds + 5120;       // [64][80]
  u16* vs   = lds + 10240;      // [64][80]
  u16* kst1 = lds + 15360;      // [64][80]  e1-weighted K^T
  u16* kst2 = lds + 20480;      // [64][80]  e2-weighted K^T
  u16* v0t  = lds + 25600;      // [80][80]  V^T + ones row (kv=64), rows 65..79 = 0
  u16* amt  = lds + 32000;      // [64][80]  decay-masked QK^T (bf16)
  u16* scr  = lds;              // [80][80] transpose scratch, aliases qs+ks
  __shared__ float lw[64], e1[64], e2[64];

  const size_t rowbase = ((size_t)(b * Tq + c * 64)) * Dq + h * 64;
  #pragma unroll
  for (int r = 0; r < 2; ++r) {
    const int s = tid + r * 256;            // 0..511
    const int u = s >> 3, e8 = (s & 7) << 3;
    *(uint4*)(&qs[u * 80 + e8]) = *(const uint4*)(qb + rowbase + (size_t)u * Dq + e8);
    *(uint4*)(&ks[u * 80 + e8]) = *(const uint4*)(kb + rowbase + (size_t)u * Dq + e8);
    *(uint4*)(&vs[u * 80 + e8]) = *(const uint4*)(vb + rowbase + (size_t)u * Dq + e8);
  }
  if (tid < 64) {
    const float lg = llam[((size_t)(b * Tq + c * 64 + tid)) * Hq + h];
    float sum = lg;
    #pragma unroll
    for (int off = 1; off < 64; off <<= 1) {
      const float y = __shfl_up(sum, off);
      if (tid >= off) sum += y;
    }
    lw[tid] = sum;
    const float lwE = __shfl(sum, 63);
    e1[tid] = expf(lwE - sum);
    e2[tid] = expf(sum);
    lwout[((size_t)bh * NCHUNK + c) * 64 + tid] = sum;
  }
  __syncthreads();

  for (int idx = tid; idx < 4096; idx += 256) {
    const int u = idx & 63, k = idx >> 6;
    const float kv_ = bf2f(ks[u * 80 + k]);
    kst1[k * 80 + u] = f2bf(e1[u] * kv_);
    kst2[k * 80 + u] = f2bf(e2[u] * kv_);
  }
  for (int idx = tid; idx < 6400; idx += 256) {
    const int u = idx & 63, kv = idx >> 6;
    u16 val;
    if (kv < 64)       val = vs[u * 80 + kv];
    else if (kv == 64) val = (u16)0x3F80;   // 1.0 bf16
    else               val = 0;
    v0t[kv * 80 + u] = val;
  }
  __syncthreads();

  // ---- QK^T + decay mask -> amt (bf16)
  {
    f32x4 qk[4] = {};
    __builtin_amdgcn_s_setprio(1);
    #pragma unroll
    for (int s = 0; s < 2; ++s) {
      const f32x4 a = *(const f32x4*)(&qs[(16 * w + fr) * 80 + s * 32 + fq * 8]);
      #pragma unroll
      for (int n = 0; n < 4; ++n) {
        const f32x4 bb = *(const f32x4*)(&ks[(16 * n + fr) * 80 + s * 32 + fq * 8]);
        MFMA16(qk[n], a, bb);
      }
    }
    __builtin_amdgcn_s_setprio(0);
    #pragma unroll
    for (int n = 0; n < 4; ++n) {
      const float lwj = lw[16 * n + fr];
      #pragma unroll
      for (int r = 0; r < 4; ++r) {
        const int row = 16 * w + fq * 4 + r;
        const float v = qk[n][r] * expf(-fabsf(lw[row] - lwj));
        amt[row * 80 + 16 * n + fr] = f2bf(v);
      }
    }
  }
  __syncthreads();

  const size_t ob = ((size_t)bh * NCHUNK + c) * (size_t)STW;

  // ---- intra = Am @ [V | 1]
  {
    f32x4 acc5[5] = {};
    __builtin_amdgcn_s_setprio(1);
    #pragma unroll
    for (int s = 0; s < 2; ++s) {
      const f32x4 a = *(const f32x4*)(&amt[(16 * w + fr) * 80 + s * 32 + fq * 8]);
      #pragma unroll
      for (int n = 0; n < 5; ++n) {
        const f32x4 bb = *(const f32x4*)(&v0t[(16 * n + fr) * 80 + s * 32 + fq * 8]);
        MFMA16(acc5[n], a, bb);
      }
    }
    __builtin_amdgcn_s_setprio(0);
    #pragma unroll
    for (int n = 0; n < 5; ++n)
      #pragma unroll
      for (int r = 0; r < 4; ++r)
        intra[ob + (size_t)(16 * w + fq * 4 + r) * 80 + 16 * n + fr] = f2bf(acc5[n][r]);
  }

  // ---- dS, store TRANSPOSED [kv][k]
  {
    f32x4 acc5[5] = {};
    __builtin_amdgcn_s_setprio(1);
    #pragma unroll
    for (int s = 0; s < 2; ++s) {
      const f32x4 a = *(const f32x4*)(&kst1[(16 * w + fr) * 80 + s * 32 + fq * 8]);
      #pragma unroll
      for (int n = 0; n < 5; ++n) {
        const f32x4 bb = *(const f32x4*)(&v0t[(16 * n + fr) * 80 + s * 32 + fq * 8]);
        MFMA16(acc5[n], a, bb);
      }
    }
    __builtin_amdgcn_s_setprio(0);
    #pragma unroll
    for (int n = 0; n < 5; ++n)
      #pragma unroll
      for (int r = 0; r < 4; ++r)
        scr[(16 * n + fr) * 80 + (16 * w + fq * 4 + r)] = f2bf(acc5[n][r]);
  }
  __syncthreads();
  for (int i4 = tid; i4 < 640; i4 += 256) {
    const int kv = i4 >> 3, k8 = (i4 & 7) << 3;
    *(uint4*)(dS + ob + (size_t)kv * 64 + k8) = *(const uint4*)(&scr[kv * 80 + k8]);
  }
  __syncthreads();

  // ---- dR with kst2
  {
    f32x4 acc5[5] = {};
    __builtin_amdgcn_s_setprio(1);
    #pragma unroll
    for (int s = 0; s < 2; ++s) {
      const f32x4 a = *(const f32x4*)(&kst2[(16 * w + fr) * 80 + s * 32 + fq * 8]);
      #pragma unroll
      for (int n = 0; n < 5; ++n) {
        const f32x4 bb = *(const f32x4*)(&v0t[(16 * n + fr) * 80 + s * 32 + fq * 8]);
        MFMA16(acc5[n], a, bb);
      }
    }
    __builtin_amdgcn_s_setprio(0);
    #pragma unroll
    for (int n = 0; n < 5; ++n)
      #pragma unroll
      for (int r = 0; r < 4; ++r)
        scr[(16 * n + fr) * 80 + (16 * w + fq * 4 + r)] = f2bf(acc5[n][r]);
  }
  __syncthreads();
  for (int i4 = tid; i4 < 640; i4 += 256) {
    const int kv = i4 >> 3, k8 = (i4 & 7) << 3;
    *(uint4*)(dR + ob + (size_t)kv * 64 + k8) = *(const uint4*)(&scr[kv * 80 + k8]);
  }
}

// ---------------- LION phase B: per-element chunk-scan, bf16 states, fp32 carry ----------------
__global__ __launch_bounds__(256) void lion_state_kernel(
    u16* __restrict__ dS, u16* __restrict__ dR,
    const float* __restrict__ lwbuf)
{
  const int bh  = blockIdx.y >> 1;
  const int dir = blockIdx.y & 1;
  const int e   = blockIdx.x * 256 + threadIdx.x;
  float st = 0.f;
  if (dir == 0) {
    for (int c = 0; c < NCHUNK; ++c) {
      const float d = expf(lwbuf[((size_t)bh * NCHUNK + c) * 64 + 63]);
      const size_t idx = ((size_t)bh * NCHUNK + c) * (size_t)STW + e;
      const float tmp = bf2f(dS[idx]);
      dS[idx] = f2bf(st);
      st = fmaf(d, st, tmp);
    }
  } else {
    for (int c = NCHUNK - 1; c >= 0; --c) {
      const float d = expf(lwbuf[((size_t)bh * NCHUNK + c) * 64 + 63]);
      const size_t idx = ((size_t)bh * NCHUNK + c) * (size_t)STW + e;
      const float tmp = bf2f(dR[idx]);
      dR[idx] = f2bf(st);
      st = fmaf(d, st, tmp);
    }
  }
}

// ================= LION phase C (MFMA): cross terms + normalize -> attn =================
__global__ __launch_bounds__(256) void lion_cross_kernel(
    const u16* __restrict__ qb, const u16* __restrict__ intra,
    const u16* __restrict__ Sst, const u16* __restrict__ Rst,
    const float* __restrict__ lwbuf, u16* __restrict__ attn)
{
  const int c  = blockIdx.x;
  const int bh = blockIdx.y;
  const int b = bh >> 4, h = bh & 15;
  const int tid = threadIdx.x;
  const int lane = tid & 63, w = tid >> 6;
  const int fr = lane & 15, fq = lane >> 4;

  __shared__ __align__(16) u16 ldsx[17920];
  u16* qs  = ldsx;             // [64][80]
  u16* Stl = ldsx + 5120;      // [80][80]
  u16* Rtl = ldsx + 11520;     // [80][80]
  __shared__ float lw[64], den[64];

  const size_t rowbase = ((size_t)(b * Tq + c * 64)) * Dq + h * 64;
  const size_t ob = ((size_t)bh * NCHUNK + c) * (size_t)STW;
  #pragma unroll
  for (int r = 0; r < 2; ++r) {
    const int s = tid + r * 256;
    const int u = s >> 3, e8 = (s & 7) << 3;
    *(uint4*)(&qs[u * 80 + e8]) = *(const uint4*)(qb + rowbase + (size_t)u * Dq + e8);
  }
  for (int i4 = tid; i4 < 1280; i4 += 256) {
    const int hl = (i4 >= 640);
    const int j = hl ? i4 - 640 : i4;
    const int kv = j >> 3, k8 = (j & 7) << 3;
    const u16* srcp = (hl ? Rst : Sst) + ob + (size_t)kv * 64 + k8;
    u16* dstp = (hl ? Rtl : Stl) + kv * 80 + k8;
    *(uint4*)dstp = *(const uint4*)srcp;
  }
  if (tid < 64) lw[tid] = lwbuf[((size_t)bh * NCHUNK + c) * 64 + tid];
  __syncthreads();
  const float lwE = lw[63];

  f32x4 aS[5] = {}, aR[5] = {};
  __builtin_amdgcn_s_setprio(1);
  #pragma unroll
  for (int s = 0; s < 2; ++s) {
    const f32x4 a = *(const f32x4*)(&qs[(16 * w + fr) * 80 + s * 32 + fq * 8]);
    #pragma unroll
    for (int n = 0; n < 5; ++n) {
      const f32x4 sb = *(const f32x4*)(&Stl[(16 * n + fr) * 80 + s * 32 + fq * 8]);
      const f32x4 rb = *(const f32x4*)(&Rtl[(16 * n + fr) * 80 + s * 32 + fq * 8]);
      MFMA16(aS[n], a, sb);
      MFMA16(aR[n], a, rb);
    }
  }
  __builtin_amdgcn_s_setprio(0);

  float outv[5][4];
  float efr[4], ebr[4];
  #pragma unroll
  for (int r = 0; r < 4; ++r) {
    const int row = 16 * w + fq * 4 + r;
    efr[r] = expf(lw[row]);
    ebr[r] = expf(lwE - lw[row]);
  }
  #pragma unroll
  for (int n = 0; n < 5; ++n)
    #pragma unroll
    for (int r = 0; r < 4; ++r) {
      const int row = 16 * w + fq * 4 + r;
      outv[n][r] = bf2f(intra[ob + (size_t)row * 80 + 16 * n + fr])
                 + efr[r] * aS[n][r] + ebr[r] * aR[n][r];
    }
  if (fr == 0) {
    #pragma unroll
    for (int r = 0; r < 4; ++r) den[16 * w + fq * 4 + r] = outv[4][r];
  }
  __syncthreads();
  #pragma unroll
  for (int n = 0; n < 4; ++n)
    #pragma unroll
    for (int r = 0; r < 4; ++r) {
      const int row = 16 * w + fq * 4 + r;
      const float dv = fmaxf(den[row], 1e-6f);
      attn[rowbase + (size_t)row * Dq + 16 * n + fr] = f2bf(outv[n][r] / dv);
    }
}

// ---------------- launch ----------------
extern "C" void kernel_launch(void* const* d_in, const int* in_sizes, int n_in,
                              void* d_out, int out_size, void* d_ws, size_t ws_size,
                              hipStream_t stream)
{
  const float* x     = (const float*)d_in[0];
  const float* q_w   = (const float*)d_in[1];
  const float* q_b   = (const float*)d_in[2];
  const float* k_w   = (const float*)d_in[3];
  const float* k_b   = (const float*)d_in[4];
  const float* v_w   = (const float*)d_in[5];
  const float* v_b   = (const float*)d_in[6];
  const float* o_w   = (const float*)d_in[7];
  const float* o_b   = (const float*)d_in[8];
  const float* ln1_w = (const float*)d_in[9];
  const float* ln1_b = (const float*)d_in[10];
  const float* ln2_w = (const float*)d_in[11];
  const float* ln2_b = (const float*)d_in[12];
  const float* dec_w = (const float*)d_in[13];
  const float* dec_b = (const float*)d_in[14];
  const float* f1_w  = (const float*)d_in[15];
  const float* f1_b  = (const float*)d_in[16];
  const float* f2_w  = (const float*)d_in[17];
  const float* f2_b  = (const float*)d_in[18];
  float* out = (float*)d_out;
  float* ws  = (float*)d_ws;

  size_t o = 0;
  float* xa    = ws + o; o += (size_t)ROWS * Dq;               // fp32 post-attn residual
  u16*   xnb   = (u16*)(ws + o); o += (size_t)ROWS * Dq / 2;
  u16*   qbuf  = (u16*)(ws + o); o += (size_t)ROWS * Dq / 2;
  u16*   kbuf  = (u16*)(ws + o); o += (size_t)ROWS * Dq / 2;
  u16*   vbuf  = (u16*)(ws + o); o += (size_t)ROWS * Dq / 2;
  u16*   attnb = (u16*)(ws + o); o += (size_t)ROWS * Dq / 2;
  u16*   hb    = qbuf;  // FFN hidden 4096x4096 bf16 spans qbuf..attnb (ALL dead then)
  float* llam  = ws + o; o += (size_t)ROWS * Hq;
  float* lwb   = ws + o; o += (size_t)32 * NCHUNK * 64;
  u16*   dSt   = (u16*)(ws + o); o += (size_t)32 * NCHUNK * STW / 2;
  u16*   dRt   = (u16*)(ws + o); o += (size_t)32 * NCHUNK * STW / 2;
  // FFN2 split-K partials: dSt..dRt contiguous region (10.49M u16 >= 2*4.19M),
  // dead after lion_cross, disjoint from hb/xa/weights (r9 bug: vbuf overlapped hb!)
  u16*   pker  = dSt;
  u16*   intrab= (u16*)(ws + o); o += (size_t)32 * NCHUNK * STW / 2;
  u16*   x2b   = intrab;  // LN2 out aliases intrab (dead post-cross)
  u16*   qkvT  = (u16*)(ws + o); o += (size_t)3 * Dq * Dq / 2;
  u16*   owT   = (u16*)(ws + o); o += (size_t)Dq * Dq / 2;
  u16*   f1T   = (u16*)(ws + o); o += (size_t)Dq * FFNq / 2;
  u16*   f2T   = (u16*)(ws + o); o += (size_t)Dq * FFNq / 2;

  wconv_all<<<3072, 256, 0, stream>>>(q_w, k_w, v_w, o_w, f1_w, f2_w,
                                      qkvT, owT, f1T, f2T);

  ln_kernel<<<ROWS, 256, 0, stream>>>(x, ln1_w, ln1_b, xnb);
  // QKV fused: 128x128, TW=512 (8 waves, 2x4), NPH=2 (r21 champion)
  mgemm<128, 128, 512, 2, 4, 3, 1, ACT_NONE, false, false, true, 2><<<dim3(24, 32), 512, 0, stream>>>(
      xnb, qkvT, q_b, k_b, v_b, nullptr, qbuf, kbuf, vbuf, ROWS, 3072, Dq);
  declam_kernel<<<ROWS, 256, 0, stream>>>(xnb, dec_w, dec_b, llam);

  lion_chunk_kernel<<<dim3(NCHUNK, 32), 256, 0, stream>>>(qbuf, kbuf, vbuf, llam, intrab, dSt, dRt, lwb);
  lion_state_kernel<<<dim3(20, 64), 256, 0, stream>>>(dSt, dRt, lwb);
  lion_cross_kernel<<<dim3(NCHUNK, 32), 256, 0, stream>>>(qbuf, intrab, dSt, dRt, lwb, attnb);

  // O-proj: 64x64, NB=4 (depth-3 prefetch), NPH=1 (NR=2 clusters too small)
  mgemm<64, 64, 256, 2, 2, 4, 1, ACT_NONE, true, true, false, 1><<<dim3(16, 64), 256, 0, stream>>>(
      attnb, owT, o_b, nullptr, nullptr, x, xa, nullptr, nullptr, ROWS, Dq, Dq);
  ln_kernel<<<ROWS, 256, 0, stream>>>(xa, ln2_w, ln2_b, x2b);
  // FFN1: 128x256, TW=512 (8 waves 2x4), NB=3, NPH=2 — r22: grid (16,32)=512
  // = 2 blocks/CU AND 16 waves/CU (was 256^2: 1 block/CU, no inter-block overlap)
  mgemm<128, 256, 512, 2, 4, 3, 1, ACT_GELU, false, false, false, 2><<<dim3(16, 32), 512, 0, stream>>>(
      x2b, f1T, f1_b, nullptr, nullptr, nullptr, hb, nullptr, nullptr, ROWS, FFNq, Dq);
  // FFN2: split-K=2 @ 128x128, TW=512 (8 waves, 2x4), NPH=2 (r21)
  mgemm<128, 128, 512, 2, 4, 3, 2, ACT_NONE, false, false, false, 2><<<dim3(8, 32, 2), 512, 0, stream>>>(
      hb, f2T, f2_b, nullptr, nullptr, nullptr, nullptr, pker, nullptr, ROWS, Dq, FFNq);
  ffn2_reduce<<<2048, 256, 0, stream>>>(pker, f2_b, xa, out);
}

// Round 23
// 250.112 us; speedup vs baseline: 1.0114x; 1.0114x over previous
//
#include <hip/hip_runtime.h>
#include <cstdint>

#define Bq 2
#define Tq 2048
#define Dq 1024
#define Hq 16
#define FFNq 4096
#define NCHUNK 32
#define ROWS (Bq*Tq)   // 4096
#define STW 5120       // 64x80 (or 80x64) state/tile words

typedef unsigned short u16;
typedef __attribute__((ext_vector_type(4))) float f32x4;

enum { ACT_NONE = 0, ACT_ELU1 = 1, ACT_GELU = 2 };

// gfx950 unified VGPR/AGPR file: "+v" is correct (r11: "+a" regressed).
// r14: do NOT fully unroll the pipeline loop. r18: NPH=4 regressed; NPH=2 optimum.
// r20/r21: waves/CU (TLP) is the active lever; r22: 128x256 FFN1 neutral.
// FINAL: r21 champion configuration (251.06 us).
#define MFMA16(acc, a, b) \
  asm("v_mfma_f32_16x16x32_bf16 %0, %1, %2, %0" : "+v"(acc) : "v"(a), "v"(b))
#define VMWAIT(N) asm volatile("s_waitcnt vmcnt(" #N ")" ::: "memory")

__device__ __forceinline__ u16 f2bf(float f) {
  uint32_t u = __float_as_uint(f);
  uint32_t r = (u + 0x7FFFu + ((u >> 16) & 1u)) >> 16;
  return (u16)r;
}
__device__ __forceinline__ float bf2f(u16 u) {
  return __uint_as_float(((uint32_t)u) << 16);
}
__device__ __forceinline__ float bflo(uint32_t w) { return __uint_as_float(w << 16); }
__device__ __forceinline__ float bfhi(uint32_t w) { return __uint_as_float(w & 0xffff0000u); }

__device__ __forceinline__ void gload16(const void* g, void* l) {
  __builtin_amdgcn_global_load_lds(
      (const __attribute__((address_space(1))) uint32_t*)g,
      (__attribute__((address_space(3))) uint32_t*)l, 16, 0, 0);
}

// bijective XCD swizzle (nwg % 8 == 0 for all our grids)
__device__ __forceinline__ void xcd_swizzle(int& bx, int& by) {
  const int gx = gridDim.x;
  const int nwg = gx * gridDim.y;
  int flat = by * gx + bx;
  flat = (flat & 7) * (nwg >> 3) + (flat >> 3);
  bx = flat % gx;
  by = flat / gx;
}

// ---------------- merged weight convert+transpose: 6 matrices, one launch ----------------
__global__ __launch_bounds__(256) void wconv_all(
    const float* __restrict__ q_w, const float* __restrict__ k_w,
    const float* __restrict__ v_w, const float* __restrict__ o_w,
    const float* __restrict__ f1_w, const float* __restrict__ f2_w,
    u16* __restrict__ qkvT, u16* __restrict__ owT,
    u16* __restrict__ f1T, u16* __restrict__ f2T)
{
  const int bid = blockIdx.x;
  const float* src; u16* dst; int Kd, N, bx, by;
  if (bid < 1024) {          // q,k,v,o: 4 x 256 tiles (1024x1024)
    const int m = bid >> 8, t = bid & 255;
    src = (m == 0) ? q_w : (m == 1) ? k_w : (m == 2) ? v_w : o_w;
    dst = (m == 3) ? owT : qkvT + (size_t)m * 1024 * 1024;
    Kd = 1024; N = 1024; bx = t & 15; by = t >> 4;
  } else if (bid < 2048) {   // f1: 1024x4096
    const int t = bid - 1024;
    src = f1_w; dst = f1T; Kd = 1024; N = 4096; bx = t & 63; by = t >> 6;
  } else {                   // f2: 4096x1024
    const int t = bid - 2048;
    src = f2_w; dst = f2T; Kd = 4096; N = 1024; bx = t & 15; by = t >> 4;
  }
  __shared__ float tb[64][65];
  const int n0 = bx * 64, k0 = by * 64;
  const int tid = threadIdx.x;
  #pragma unroll
  for (int r = 0; r < 4; ++r) {
    const int s = tid + r * 256;           // 0..1023
    const int kk = s >> 4, nn = (s & 15) << 2;
    const float4 v = *(const float4*)(src + (size_t)(k0 + kk) * N + n0 + nn);
    tb[kk][nn] = v.x; tb[kk][nn+1] = v.y; tb[kk][nn+2] = v.z; tb[kk][nn+3] = v.w;
  }
  __syncthreads();
  const int n = tid >> 2;
  const int ks = (tid & 3) << 4;
  uint32_t pk[8];
  #pragma unroll
  for (int j = 0; j < 8; ++j) {
    const float a = tb[ks + 2*j][n];
    const float c = tb[ks + 2*j + 1][n];
    pk[j] = (uint32_t)f2bf(a) | ((uint32_t)f2bf(c) << 16);
  }
  u16* drow = dst + (size_t)(n0 + n) * Kd + k0 + ks;
  *(uint4*)(drow)     = make_uint4(pk[0], pk[1], pk[2], pk[3]);
  *(uint4*)(drow + 8) = make_uint4(pk[4], pk[5], pk[6], pk[7]);
}

// ---------------- LayerNorm: fp32 in, bf16 out ----------------
__global__ __launch_bounds__(256) void ln_kernel(
    const float* __restrict__ x, const float* __restrict__ w,
    const float* __restrict__ b, u16* __restrict__ outb)
{
  const int row = blockIdx.x;
  const int tid = threadIdx.x;
  const float* xr = x + (size_t)row * Dq;
  float4 v = *(const float4*)(xr + tid * 4);
  float s  = v.x + v.y + v.z + v.w;
  float s2 = v.x*v.x + v.y*v.y + v.z*v.z + v.w*v.w;
  #pragma unroll
  for (int off = 32; off > 0; off >>= 1) {
    s  += __shfl_down(s,  off);
    s2 += __shfl_down(s2, off);
  }
  __shared__ float rs[4], rs2[4];
  const int wid = tid >> 6, lane = tid & 63;
  if (lane == 0) { rs[wid] = s; rs2[wid] = s2; }
  __syncthreads();
  const float ts  = rs[0] + rs[1] + rs[2] + rs[3];
  const float ts2 = rs2[0] + rs2[1] + rs2[2] + rs2[3];
  const float mean = ts * (1.f / Dq);
  const float var  = ts2 * (1.f / Dq) - mean * mean;
  const float rstd = rsqrtf(var + 1e-5f);
  const float4 wv = *(const float4*)(w + tid * 4);
  const float4 bv = *(const float4*)(b + tid * 4);
  float4 o;
  o.x = (v.x - mean) * rstd * wv.x + bv.x;
  o.y = (v.y - mean) * rstd * wv.y + bv.y;
  o.z = (v.z - mean) * rstd * wv.z + bv.z;
  o.w = (v.w - mean) * rstd * wv.w + bv.w;
  uint2 p;
  p.x = (uint32_t)f2bf(o.x) | ((uint32_t)f2bf(o.y) << 16);
  p.y = (uint32_t)f2bf(o.z) | ((uint32_t)f2bf(o.w) << 16);
  *(uint2*)(outb + (size_t)row * Dq + tid * 4) = p;
}

// ============ bf16 MFMA GEMM: geometry+depth+splitK templated, NB buffers ============
// NPH=2 sub-phases per K-step (r16/r17-validated T3->T5 mechanism; r18: NPH=4
// regressed): {read A+B1, stageA, bar, setprio MFMA half} {read B2, stageB,
// bar, setprio MFMA half} — same buffer/vmcnt invariants as the base loop.
template<int BM, int BN, int TW, int WM, int WN, int NB, int SK, int ACT,
         bool RES, bool F32OUT, bool QKVMODE, int NPH = 1>
__global__ __launch_bounds__(TW) void mgemm(
    const u16* __restrict__ A, const u16* __restrict__ BT,
    const float* __restrict__ b0, const float* __restrict__ b1,
    const float* __restrict__ b2, const float* __restrict__ res,
    void* __restrict__ C0, void* __restrict__ C1, void* __restrict__ C2,
    int M, int N, int Kd)
{
  constexpr int GA = (BM * 32) / (TW * 8);   // A gloads/thread/stage
  constexpr int GB = (BN * 32) / (TW * 8);
  constexpr int L  = GA + GB;
  constexpr int MR = BM / WM / 16;
  constexpr int NR = BN / WN / 16;
  constexpr int VMAIN = (NB - 2) * L;        // steady-state wait
  __shared__ u16 As[NB][BM * 32];
  __shared__ u16 Bs[NB][BN * 32];
  const int tid = threadIdx.x;
  const int lane = tid & 63, wid = tid >> 6;
  const int wr = wid / WN, wc = wid % WN;
  int bx = blockIdx.x, by = blockIdx.y;
  xcd_swizzle(bx, by);
  const int rowBase = by * BM;
  const int colBase = bx * BN;
  const int bz  = (SK > 1) ? (int)blockIdx.z : 0;
  const int kb0 = bz * (Kd / SK);

  f32x4 acc[MR][NR] = {};

  const int srow = tid >> 2;                                  // 0..TW/4-1
  const int skb  = (((tid & 3) ^ ((tid >> 3) & 3)) << 3);     // pre-swizzled source
  const u16* ag[GA];
  const u16* bg[GB];
  #pragma unroll
  for (int g = 0; g < GA; ++g)
    ag[g] = A  + (size_t)(rowBase + g * (TW / 4) + srow) * Kd + kb0 + skb;
  #pragma unroll
  for (int g = 0; g < GB; ++g)
    bg[g] = BT + (size_t)(colBase + g * (TW / 4) + srow) * Kd + kb0 + skb;

  const int fr = lane & 15, fq = lane >> 4;
  const int rsw = (fq ^ ((fr >> 1) & 3)) * 8;                 // swizzled read

  auto STAGE_A = [&](int buf, int k0) {
    #pragma unroll
    for (int g = 0; g < GA; ++g) gload16(ag[g] + k0, &As[buf][(g * TW + tid) * 8]);
  };
  auto STAGE_B = [&](int buf, int k0) {
    #pragma unroll
    for (int g = 0; g < GB; ++g) gload16(bg[g] + k0, &Bs[buf][(g * TW + tid) * 8]);
  };

  const int NT = (Kd / SK) >> 5;
  #pragma unroll
  for (int s = 0; s < NB - 1; ++s) { STAGE_A(s, s << 5); STAGE_B(s, s << 5); }
  int cur = 0, wbuf = NB - 1;
  for (int t = 0; t < NT; ++t) {
    const int rem = NT - t;
    if (rem >= NB - 1) {
      if constexpr (VMAIN == 2)      VMWAIT(2);
      else if constexpr (VMAIN == 3) VMWAIT(3);
      else if constexpr (VMAIN == 4) VMWAIT(4);
      else if constexpr (VMAIN == 6) VMWAIT(6);
      else                           VMWAIT(8);
    } else if (NB >= 4 && rem == 2) {
      if constexpr (L == 2)      VMWAIT(2);
      else if constexpr (L == 3) VMWAIT(3);
      else                       VMWAIT(4);
    } else {
      VMWAIT(0);
    }
    __builtin_amdgcn_s_barrier();
    asm volatile("" ::: "memory");
    const bool pf = (t + NB - 1 < NT);
    const int  pk = (t + NB - 1) << 5;
    if constexpr (NPH == 2) {
      f32x4 af[MR], bf_[NR];
      #pragma unroll
      for (int m = 0; m < MR; ++m)
        af[m] = *(const f32x4*)(&As[cur][(wr * (BM / WM) + m * 16 + fr) * 32 + rsw]);
      #pragma unroll
      for (int n = 0; n < NR / 2; ++n)
        bf_[n] = *(const f32x4*)(&Bs[cur][(wc * (BN / WN) + n * 16 + fr) * 32 + rsw]);
      if (pf) STAGE_A(wbuf, pk);
      __builtin_amdgcn_s_barrier();
      asm volatile("" ::: "memory");
      __builtin_amdgcn_s_setprio(1);
      #pragma unroll
      for (int m = 0; m < MR; ++m)
        #pragma unroll
        for (int n = 0; n < NR / 2; ++n)
          MFMA16(acc[m][n], af[m], bf_[n]);
      __builtin_amdgcn_s_setprio(0);
      #pragma unroll
      for (int n = NR / 2; n < NR; ++n)
        bf_[n] = *(const f32x4*)(&Bs[cur][(wc * (BN / WN) + n * 16 + fr) * 32 + rsw]);
      if (pf) STAGE_B(wbuf, pk);
      __builtin_amdgcn_s_barrier();
      asm volatile("" ::: "memory");
      __builtin_amdgcn_s_setprio(1);
      #pragma unroll
      for (int m = 0; m < MR; ++m)
        #pragma unroll
        for (int n = NR / 2; n < NR; ++n)
          MFMA16(acc[m][n], af[m], bf_[n]);
      __builtin_amdgcn_s_setprio(0);
      asm volatile("" ::: "memory");
    } else {
      if (pf) { STAGE_A(wbuf, pk); STAGE_B(wbuf, pk); }
      f32x4 af[MR], bf_[NR];
      #pragma unroll
      for (int m = 0; m < MR; ++m)
        af[m] = *(const f32x4*)(&As[cur][(wr * (BM / WM) + m * 16 + fr) * 32 + rsw]);
      #pragma unroll
      for (int n = 0; n < NR; ++n)
        bf_[n] = *(const f32x4*)(&Bs[cur][(wc * (BN / WN) + n * 16 + fr) * 32 + rsw]);
      #pragma unroll
      for (int m = 0; m < MR; ++m)
        #pragma unroll
        for (int n = 0; n < NR; ++n)
          MFMA16(acc[m][n], af[m], bf_[n]);
      asm volatile("" ::: "memory");
    }
    cur  = (cur  == NB - 1) ? 0 : cur + 1;
    wbuf = (wbuf == NB - 1) ? 0 : wbuf + 1;
  }

  if constexpr (SK > 1) {
    u16* pp = (u16*)C1 + (size_t)bz * ((size_t)M * N);   // contiguous dead region
    #pragma unroll
    for (int m = 0; m < MR; ++m) {
      #pragma unroll
      for (int n = 0; n < NR; ++n) {
        const int col = colBase + wc * (BN / WN) + n * 16 + fr;
        #pragma unroll
        for (int r = 0; r < 4; ++r) {
          const int row = rowBase + wr * (BM / WM) + m * 16 + fq * 4 + r;
          pp[(size_t)row * N + col] = f2bf(acc[m][n][r]);
        }
      }
    }
  } else if constexpr (QKVMODE) {
    const int wtype = colBase >> 10;               // 0=q 1=k 2=v (block-uniform)
    const float* bp = (wtype == 0) ? b0 : (wtype == 1) ? b1 : b2;
    u16* outp = (u16*)((wtype == 0) ? C0 : (wtype == 1) ? C1 : C2);
    const int colB = colBase & 1023;
    #pragma unroll
    for (int m = 0; m < MR; ++m) {
      #pragma unroll
      for (int n = 0; n < NR; ++n) {
        const int col = colB + wc * (BN / WN) + n * 16 + fr;
        const float bv = bp[col];
        #pragma unroll
        for (int r = 0; r < 4; ++r) {
          const int row = rowBase + wr * (BM / WM) + m * 16 + fq * 4 + r;
          float val = acc[m][n][r] + bv;
          if (wtype < 2) val = (val >= 0.f) ? (val + 1.f) : expf(val);
          outp[(size_t)row * Dq + col] = f2bf(val);
        }
      }
    }
  } else {
    #pragma unroll
    for (int m = 0; m < MR; ++m) {
      #pragma unroll
      for (int n = 0; n < NR; ++n) {
        const int col = colBase + wc * (BN / WN) + n * 16 + fr;
        const float bv = b0[col];
        #pragma unroll
        for (int r = 0; r < 4; ++r) {
          const int row = rowBase + wr * (BM / WM) + m * 16 + fq * 4 + r;
          float val = acc[m][n][r] + bv;
          if (ACT == ACT_ELU1)      val = (val >= 0.f) ? (val + 1.f) : expf(val);
          else if (ACT == ACT_GELU) val = 0.5f * val * (1.f + erff(val * 0.70710678118f));
          if (RES) val += res[(size_t)row * N + col];
          if (F32OUT) ((float*)C0)[(size_t)row * N + col] = val;
          else        ((u16*)C0)[(size_t)row * N + col] = f2bf(val);
        }
      }
    }
  }
}

// ---------------- FFN2 split-K reduce: out = p0 + p1 + bias + res ----------------
__global__ __launch_bounds__(256) void ffn2_reduce(
    const u16* __restrict__ p, const float* __restrict__ bias,
    const float* __restrict__ res, float* __restrict__ out)
{
  const size_t base = ((size_t)blockIdx.x * 256 + threadIdx.x) * 8;
  const size_t MN = (size_t)ROWS * Dq;
  const uint4 a0 = *(const uint4*)(p + base);
  const uint4 a1 = *(const uint4*)(p + MN + base);
  const int col = (int)(base & (Dq - 1));
  float r[8];
  const uint32_t w0[4] = {a0.x, a0.y, a0.z, a0.w};
  const uint32_t w1[4] = {a1.x, a1.y, a1.z, a1.w};
  #pragma unroll
  for (int j = 0; j < 4; ++j) {
    r[2*j]   = bflo(w0[j]) + bflo(w1[j]);
    r[2*j+1] = bfhi(w0[j]) + bfhi(w1[j]);
  }
  const float4 x0 = *(const float4*)(res + base);
  const float4 x1 = *(const float4*)(res + base + 4);
  float4 o0, o1;
  o0.x = r[0] + bias[col+0] + x0.x;  o0.y = r[1] + bias[col+1] + x0.y;
  o0.z = r[2] + bias[col+2] + x0.z;  o0.w = r[3] + bias[col+3] + x0.w;
  o1.x = r[4] + bias[col+4] + x1.x;  o1.y = r[5] + bias[col+5] + x1.y;
  o1.z = r[6] + bias[col+6] + x1.z;  o1.w = r[7] + bias[col+7] + x1.w;
  *(float4*)(out + base)     = o0;
  *(float4*)(out + base + 4) = o1;
}

// ---------------- decay head (reads bf16 xn) ----------------
__global__ __launch_bounds__(256) void declam_kernel(
    const u16* __restrict__ xn, const float* __restrict__ dec_w,
    const float* __restrict__ dec_b, float* __restrict__ llam)
{
  const int row = blockIdx.x;
  const int tid = threadIdx.x;
  const int h = tid & 15, part = tid >> 4;
  const u16* xr = xn + (size_t)row * Dq;
  float s = 0.f;
  #pragma unroll 4
  for (int i = 0; i < 64; ++i) {
    const int d = part * 64 + i;
    s += bf2f(xr[d]) * dec_w[d * Hq + h];
  }
  __shared__ float ps[256];
  ps[tid] = s;
  __syncthreads();
  if (tid < 16) {
    float t = dec_b[tid];
    #pragma unroll
    for (int p = 0; p < 16; ++p) t += ps[p * 16 + tid];
    float lam = 1.f / (1.f + expf(-t));
    lam = fmaxf(lam, 1e-8f);
    llam[(size_t)row * Hq + tid] = logf(lam);
  }
}

// ================= LION phase A (MFMA): intra + transposed state deltas =================
__global__ __launch_bounds__(256) void lion_chunk_kernel(
    const u16* __restrict__ qb, const u16* __restrict__ kb,
    const u16* __restrict__ vb, const float* __restrict__ llam,
    u16* __restrict__ intra, u16* __restrict__ dS,
    u16* __restrict__ dR, float* __restrict__ lwout)
{
  const int c  = blockIdx.x;
  const int bh = blockIdx.y;
  const int b = bh >> 4, h = bh & 15;
  const int tid = threadIdx.x;
  const int lane = tid & 63, w = tid >> 6;
  const int fr = lane & 15, fq = lane >> 4;

  __shared__ __align__(16) u16 lds[37120];
  u16* qs   = lds;              // [64][80]
  u16* ks   = lds + 5120;       // [64][80]
  u16* vs   = lds + 10240;      // [64][80]
  u16* kst1 = lds + 15360;      // [64][80]  e1-weighted K^T
  u16* kst2 = lds + 20480;      // [64][80]  e2-weighted K^T
  u16* v0t  = lds + 25600;      // [80][80]  V^T + ones row (kv=64), rows 65..79 = 0
  u16* amt  = lds + 32000;      // [64][80]  decay-masked QK^T (bf16)
  u16* scr  = lds;              // [80][80] transpose scratch, aliases qs+ks
  __shared__ float lw[64], e1[64], e2[64];

  const size_t rowbase = ((size_t)(b * Tq + c * 64)) * Dq + h * 64;
  #pragma unroll
  for (int r = 0; r < 2; ++r) {
    const int s = tid + r * 256;            // 0..511
    const int u = s >> 3, e8 = (s & 7) << 3;
    *(uint4*)(&qs[u * 80 + e8]) = *(const uint4*)(qb + rowbase + (size_t)u * Dq + e8);
    *(uint4*)(&ks[u * 80 + e8]) = *(const uint4*)(kb + rowbase + (size_t)u * Dq + e8);
    *(uint4*)(&vs[u * 80 + e8]) = *(const uint4*)(vb + rowbase + (size_t)u * Dq + e8);
  }
  if (tid < 64) {
    const float lg = llam[((size_t)(b * Tq + c * 64 + tid)) * Hq + h];
    float sum = lg;
    #pragma unroll
    for (int off = 1; off < 64; off <<= 1) {
      const float y = __shfl_up(sum, off);
      if (tid >= off) sum += y;
    }
    lw[tid] = sum;
    const float lwE = __shfl(sum, 63);
    e1[tid] = expf(lwE - sum);
    e2[tid] = expf(sum);
    lwout[((size_t)bh * NCHUNK + c) * 64 + tid] = sum;
  }
  __syncthreads();

  for (int idx = tid; idx < 4096; idx += 256) {
    const int u = idx & 63, k = idx >> 6;
    const float kv_ = bf2f(ks[u * 80 + k]);
    kst1[k * 80 + u] = f2bf(e1[u] * kv_);
    kst2[k * 80 + u] = f2bf(e2[u] * kv_);
  }
  for (int idx = tid; idx < 6400; idx += 256) {
    const int u = idx & 63, kv = idx >> 6;
    u16 val;
    if (kv < 64)       val = vs[u * 80 + kv];
    else if (kv == 64) val = (u16)0x3F80;   // 1.0 bf16
    else               val = 0;
    v0t[kv * 80 + u] = val;
  }
  __syncthreads();

  // ---- QK^T + decay mask -> amt (bf16)
  {
    f32x4 qk[4] = {};
    __builtin_amdgcn_s_setprio(1);
    #pragma unroll
    for (int s = 0; s < 2; ++s) {
      const f32x4 a = *(const f32x4*)(&qs[(16 * w + fr) * 80 + s * 32 + fq * 8]);
      #pragma unroll
      for (int n = 0; n < 4; ++n) {
        const f32x4 bb = *(const f32x4*)(&ks[(16 * n + fr) * 80 + s * 32 + fq * 8]);
        MFMA16(qk[n], a, bb);
      }
    }
    __builtin_amdgcn_s_setprio(0);
    #pragma unroll
    for (int n = 0; n < 4; ++n) {
      const float lwj = lw[16 * n + fr];
      #pragma unroll
      for (int r = 0; r < 4; ++r) {
        const int row = 16 * w + fq * 4 + r;
        const float v = qk[n][r] * expf(-fabsf(lw[row] - lwj));
        amt[row * 80 + 16 * n + fr] = f2bf(v);
      }
    }
  }
  __syncthreads();

  const size_t ob = ((size_t)bh * NCHUNK + c) * (size_t)STW;

  // ---- intra = Am @ [V | 1]
  {
    f32x4 acc5[5] = {};
    __builtin_amdgcn_s_setprio(1);
    #pragma unroll
    for (int s = 0; s < 2; ++s) {
      const f32x4 a = *(const f32x4*)(&amt[(16 * w + fr) * 80 + s * 32 + fq * 8]);
      #pragma unroll
      for (int n = 0; n < 5; ++n) {
        const f32x4 bb = *(const f32x4*)(&v0t[(16 * n + fr) * 80 + s * 32 + fq * 8]);
        MFMA16(acc5[n], a, bb);
      }
    }
    __builtin_amdgcn_s_setprio(0);
    #pragma unroll
    for (int n = 0; n < 5; ++n)
      #pragma unroll
      for (int r = 0; r < 4; ++r)
        intra[ob + (size_t)(16 * w + fq * 4 + r) * 80 + 16 * n + fr] = f2bf(acc5[n][r]);
  }

  // ---- dS, store TRANSPOSED [kv][k]
  {
    f32x4 acc5[5] = {};
    __builtin_amdgcn_s_setprio(1);
    #pragma unroll
    for (int s = 0; s < 2; ++s) {
      const f32x4 a = *(const f32x4*)(&kst1[(16 * w + fr) * 80 + s * 32 + fq * 8]);
      #pragma unroll
      for (int n = 0; n < 5; ++n) {
        const f32x4 bb = *(const f32x4*)(&v0t[(16 * n + fr) * 80 + s * 32 + fq * 8]);
        MFMA16(acc5[n], a, bb);
      }
    }
    __builtin_amdgcn_s_setprio(0);
    #pragma unroll
    for (int n = 0; n < 5; ++n)
      #pragma unroll
      for (int r = 0; r < 4; ++r)
        scr[(16 * n + fr) * 80 + (16 * w + fq * 4 + r)] = f2bf(acc5[n][r]);
  }
  __syncthreads();
  for (int i4 = tid; i4 < 640; i4 += 256) {
    const int kv = i4 >> 3, k8 = (i4 & 7) << 3;
    *(uint4*)(dS + ob + (size_t)kv * 64 + k8) = *(const uint4*)(&scr[kv * 80 + k8]);
  }
  __syncthreads();

  // ---- dR with kst2
  {
    f32x4 acc5[5] = {};
    __builtin_amdgcn_s_setprio(1);
    #pragma unroll
    for (int s = 0; s < 2; ++s) {
      const f32x4 a = *(const f32x4*)(&kst2[(16 * w + fr) * 80 + s * 32 + fq * 8]);
      #pragma unroll
      for (int n = 0; n < 5; ++n) {
        const f32x4 bb = *(const f32x4*)(&v0t[(16 * n + fr) * 80 + s * 32 + fq * 8]);
        MFMA16(acc5[n], a, bb);
      }
    }
    __builtin_amdgcn_s_setprio(0);
    #pragma unroll
    for (int n = 0; n < 5; ++n)
      #pragma unroll
      for (int r = 0; r < 4; ++r)
        scr[(16 * n + fr) * 80 + (16 * w + fq * 4 + r)] = f2bf(acc5[n][r]);
  }
  __syncthreads();
  for (int i4 = tid; i4 < 640; i4 += 256) {
    const int kv = i4 >> 3, k8 = (i4 & 7) << 3;
    *(uint4*)(dR + ob + (size_t)kv * 64 + k8) = *(const uint4*)(&scr[kv * 80 + k8]);
  }
}

// ---------------- LION phase B: per-element chunk-scan, bf16 states, fp32 carry ----------------
__global__ __launch_bounds__(256) void lion_state_kernel(
    u16* __restrict__ dS, u16* __restrict__ dR,
    const float* __restrict__ lwbuf)
{
  const int bh  = blockIdx.y >> 1;
  const int dir = blockIdx.y & 1;
  const int e   = blockIdx.x * 256 + threadIdx.x;
  float st = 0.f;
  if (dir == 0) {
    for (int c = 0; c < NCHUNK; ++c) {
      const float d = expf(lwbuf[((size_t)bh * NCHUNK + c) * 64 + 63]);
      const size_t idx = ((size_t)bh * NCHUNK + c) * (size_t)STW + e;
      const float tmp = bf2f(dS[idx]);
      dS[idx] = f2bf(st);
      st = fmaf(d, st, tmp);
    }
  } else {
    for (int c = NCHUNK - 1; c >= 0; --c) {
      const float d = expf(lwbuf[((size_t)bh * NCHUNK + c) * 64 + 63]);
      const size_t idx = ((size_t)bh * NCHUNK + c) * (size_t)STW + e;
      const float tmp = bf2f(dR[idx]);
      dR[idx] = f2bf(st);
      st = fmaf(d, st, tmp);
    }
  }
}

// ================= LION phase C (MFMA): cross terms + normalize -> attn =================
__global__ __launch_bounds__(256) void lion_cross_kernel(
    const u16* __restrict__ qb, const u16* __restrict__ intra,
    const u16* __restrict__ Sst, const u16* __restrict__ Rst,
    const float* __restrict__ lwbuf, u16* __restrict__ attn)
{
  const int c  = blockIdx.x;
  const int bh = blockIdx.y;
  const int b = bh >> 4, h = bh & 15;
  const int tid = threadIdx.x;
  const int lane = tid & 63, w = tid >> 6;
  const int fr = lane & 15, fq = lane >> 4;

  __shared__ __align__(16) u16 ldsx[17920];
  u16* qs  = ldsx;             // [64][80]
  u16* Stl = ldsx + 5120;      // [80][80]
  u16* Rtl = ldsx + 11520;     // [80][80]
  __shared__ float lw[64], den[64];

  const size_t rowbase = ((size_t)(b * Tq + c * 64)) * Dq + h * 64;
  const size_t ob = ((size_t)bh * NCHUNK + c) * (size_t)STW;
  #pragma unroll
  for (int r = 0; r < 2; ++r) {
    const int s = tid + r * 256;
    const int u = s >> 3, e8 = (s & 7) << 3;
    *(uint4*)(&qs[u * 80 + e8]) = *(const uint4*)(qb + rowbase + (size_t)u * Dq + e8);
  }
  for (int i4 = tid; i4 < 1280; i4 += 256) {
    const int hl = (i4 >= 640);
    const int j = hl ? i4 - 640 : i4;
    const int kv = j >> 3, k8 = (j & 7) << 3;
    const u16* srcp = (hl ? Rst : Sst) + ob + (size_t)kv * 64 + k8;
    u16* dstp = (hl ? Rtl : Stl) + kv * 80 + k8;
    *(uint4*)dstp = *(const uint4*)srcp;
  }
  if (tid < 64) lw[tid] = lwbuf[((size_t)bh * NCHUNK + c) * 64 + tid];
  __syncthreads();
  const float lwE = lw[63];

  f32x4 aS[5] = {}, aR[5] = {};
  __builtin_amdgcn_s_setprio(1);
  #pragma unroll
  for (int s = 0; s < 2; ++s) {
    const f32x4 a = *(const f32x4*)(&qs[(16 * w + fr) * 80 + s * 32 + fq * 8]);
    #pragma unroll
    for (int n = 0; n < 5; ++n) {
      const f32x4 sb = *(const f32x4*)(&Stl[(16 * n + fr) * 80 + s * 32 + fq * 8]);
      const f32x4 rb = *(const f32x4*)(&Rtl[(16 * n + fr) * 80 + s * 32 + fq * 8]);
      MFMA16(aS[n], a, sb);
      MFMA16(aR[n], a, rb);
    }
  }
  __builtin_amdgcn_s_setprio(0);

  float outv[5][4];
  float efr[4], ebr[4];
  #pragma unroll
  for (int r = 0; r < 4; ++r) {
    const int row = 16 * w + fq * 4 + r;
    efr[r] = expf(lw[row]);
    ebr[r] = expf(lwE - lw[row]);
  }
  #pragma unroll
  for (int n = 0; n < 5; ++n)
    #pragma unroll
    for (int r = 0; r < 4; ++r) {
      const int row = 16 * w + fq * 4 + r;
      outv[n][r] = bf2f(intra[ob + (size_t)row * 80 + 16 * n + fr])
                 + efr[r] * aS[n][r] + ebr[r] * aR[n][r];
    }
  if (fr == 0) {
    #pragma unroll
    for (int r = 0; r < 4; ++r) den[16 * w + fq * 4 + r] = outv[4][r];
  }
  __syncthreads();
  #pragma unroll
  for (int n = 0; n < 4; ++n)
    #pragma unroll
    for (int r = 0; r < 4; ++r) {
      const int row = 16 * w + fq * 4 + r;
      const float dv = fmaxf(den[row], 1e-6f);
      attn[rowbase + (size_t)row * Dq + 16 * n + fr] = f2bf(outv[n][r] / dv);
    }
}

// ---------------- launch ----------------
extern "C" void kernel_launch(void* const* d_in, const int* in_sizes, int n_in,
                              void* d_out, int out_size, void* d_ws, size_t ws_size,
                              hipStream_t stream)
{
  const float* x     = (const float*)d_in[0];
  const float* q_w   = (const float*)d_in[1];
  const float* q_b   = (const float*)d_in[2];
  const float* k_w   = (const float*)d_in[3];
  const float* k_b   = (const float*)d_in[4];
  const float* v_w   = (const float*)d_in[5];
  const float* v_b   = (const float*)d_in[6];
  const float* o_w   = (const float*)d_in[7];
  const float* o_b   = (const float*)d_in[8];
  const float* ln1_w = (const float*)d_in[9];
  const float* ln1_b = (const float*)d_in[10];
  const float* ln2_w = (const float*)d_in[11];
  const float* ln2_b = (const float*)d_in[12];
  const float* dec_w = (const float*)d_in[13];
  const float* dec_b = (const float*)d_in[14];
  const float* f1_w  = (const float*)d_in[15];
  const float* f1_b  = (const float*)d_in[16];
  const float* f2_w  = (const float*)d_in[17];
  const float* f2_b  = (const float*)d_in[18];
  float* out = (float*)d_out;
  float* ws  = (float*)d_ws;

  size_t o = 0;
  float* xa    = ws + o; o += (size_t)ROWS * Dq;               // fp32 post-attn residual
  u16*   xnb   = (u16*)(ws + o); o += (size_t)ROWS * Dq / 2;
  u16*   qbuf  = (u16*)(ws + o); o += (size_t)ROWS * Dq / 2;
  u16*   kbuf  = (u16*)(ws + o); o += (size_t)ROWS * Dq / 2;
  u16*   vbuf  = (u16*)(ws + o); o += (size_t)ROWS * Dq / 2;
  u16*   attnb = (u16*)(ws + o); o += (size_t)ROWS * Dq / 2;
  u16*   hb    = qbuf;  // FFN hidden 4096x4096 bf16 spans qbuf..attnb (ALL dead then)
  float* llam  = ws + o; o += (size_t)ROWS * Hq;
  float* lwb   = ws + o; o += (size_t)32 * NCHUNK * 64;
  u16*   dSt   = (u16*)(ws + o); o += (size_t)32 * NCHUNK * STW / 2;
  u16*   dRt   = (u16*)(ws + o); o += (size_t)32 * NCHUNK * STW / 2;
  // FFN2 split-K partials: dSt..dRt contiguous region (10.49M u16 >= 2*4.19M),
  // dead after lion_cross, disjoint from hb/xa/weights (r9 bug: vbuf overlapped hb!)
  u16*   pker  = dSt;
  u16*   intrab= (u16*)(ws + o); o += (size_t)32 * NCHUNK * STW / 2;
  u16*   x2b   = intrab;  // LN2 out aliases intrab (dead post-cross)
  u16*   qkvT  = (u16*)(ws + o); o += (size_t)3 * Dq * Dq / 2;
  u16*   owT   = (u16*)(ws + o); o += (size_t)Dq * Dq / 2;
  u16*   f1T   = (u16*)(ws + o); o += (size_t)Dq * FFNq / 2;
  u16*   f2T   = (u16*)(ws + o); o += (size_t)Dq * FFNq / 2;

  wconv_all<<<3072, 256, 0, stream>>>(q_w, k_w, v_w, o_w, f1_w, f2_w,
                                      qkvT, owT, f1T, f2T);

  ln_kernel<<<ROWS, 256, 0, stream>>>(x, ln1_w, ln1_b, xnb);
  // QKV fused: 128x128, TW=512 (8 waves, 2x4), NPH=2 (r21 champion)
  mgemm<128, 128, 512, 2, 4, 3, 1, ACT_NONE, false, false, true, 2><<<dim3(24, 32), 512, 0, stream>>>(
      xnb, qkvT, q_b, k_b, v_b, nullptr, qbuf, kbuf, vbuf, ROWS, 3072, Dq);
  declam_kernel<<<ROWS, 256, 0, stream>>>(xnb, dec_w, dec_b, llam);

  lion_chunk_kernel<<<dim3(NCHUNK, 32), 256, 0, stream>>>(qbuf, kbuf, vbuf, llam, intrab, dSt, dRt, lwb);
  lion_state_kernel<<<dim3(20, 64), 256, 0, stream>>>(dSt, dRt, lwb);
  lion_cross_kernel<<<dim3(NCHUNK, 32), 256, 0, stream>>>(qbuf, intrab, dSt, dRt, lwb, attnb);

  // O-proj: 64x64, NB=4 (depth-3 prefetch), NPH=1 (NR=2 clusters too small)
  mgemm<64, 64, 256, 2, 2, 4, 1, ACT_NONE, true, true, false, 1><<<dim3(16, 64), 256, 0, stream>>>(
      attnb, owT, o_b, nullptr, nullptr, x, xa, nullptr, nullptr, ROWS, Dq, Dq);
  ln_kernel<<<ROWS, 256, 0, stream>>>(xa, ln2_w, ln2_b, x2b);
  // FFN1: 256x256, 16 waves (4x4, TW=1024), NB=3, NPH=2 (r20/r21 champion)
  mgemm<256, 256, 1024, 4, 4, 3, 1, ACT_GELU, false, false, false, 2><<<dim3(16, 16), 1024, 0, stream>>>(
      x2b, f1T, f1_b, nullptr, nullptr, nullptr, hb, nullptr, nullptr, ROWS, FFNq, Dq);
  // FFN2: split-K=2 @ 128x128, TW=512 (8 waves, 2x4), NPH=2 (r21 champion)
  mgemm<128, 128, 512, 2, 4, 3, 2, ACT_NONE, false, false, false, 2><<<dim3(8, 32, 2), 512, 0, stream>>>(
      hb, f2T, f2_b, nullptr, nullptr, nullptr, nullptr, pker, nullptr, ROWS, Dq, FFNq);
  ffn2_reduce<<<2048, 256, 0, stream>>>(pker, f2_b, xa, out);
}